// Round 4
// baseline (133.751 us; speedup 1.0000x reference)
//
#include <hip/hip_runtime.h>
#include <hip/hip_bf16.h>

typedef float f32x4  __attribute__((ext_vector_type(4)));
typedef float f32x16 __attribute__((ext_vector_type(16)));
typedef short s16x8  __attribute__((ext_vector_type(8)));

#define NB 4
#define NC 128
#define NNPOS 4096
#define KSP 8          // block-level key split
#define QBLK 256       // queries per attn block (4 waves x 64)

__device__ __forceinline__ short bf16s(float x) {
    __hip_bfloat16 h = __float2bfloat16(x);
    return *reinterpret_cast<short*>(&h);
}
__device__ __forceinline__ int packbf2(float lo, float hi) {
    __hip_bfloat162 t = __float22bfloat162_rn(float2{lo, hi});
    return *reinterpret_cast<int*>(&t);
}
__device__ __forceinline__ float bf2f(unsigned short u) {
    unsigned int v = ((unsigned int)u) << 16;
    return *reinterpret_cast<float*>(&v);
}

// ------------------------------------------------------------------
// Kernel 1: QKV projection via bf16 MFMA 16x16x32 (unchanged from R3).
// qb/kb layout: [b][n][16] bf16; vt: [b][c][n] bf16.
// ------------------------------------------------------------------
__global__ __launch_bounds__(256) void qkv_kernel(
    const float* __restrict__ x,
    const float* __restrict__ wq, const float* __restrict__ bq,
    const float* __restrict__ wk, const float* __restrict__ bk,
    const float* __restrict__ wv, const float* __restrict__ bv,
    short* __restrict__ qb, short* __restrict__ kb, short* __restrict__ vt)
{
    const int n0  = blockIdx.x * 32;
    const int b   = blockIdx.y;
    const int tid = threadIdx.x;
    const int w = tid >> 6, lane = tid & 63, quad = lane >> 4, nn = lane & 15;

    __shared__ __align__(16) short xsT[32 * 136];

    #pragma unroll
    for (int p = 0; p < 4; ++p) {
        int idx = tid + p * 256;
        int cc = idx >> 3, n4 = (idx & 7) * 4;
        f32x4 xv = *(const f32x4*)&x[((size_t)(b * NC + cc)) * NNPOS + n0 + n4];
        #pragma unroll
        for (int j = 0; j < 4; ++j)
            xsT[(n4 + j) * 136 + cc] = bf16s(xv[j]);
    }

    s16x8 af[3][4];
    bool  live[3];
    f32x4 biasv[3];
    #pragma unroll
    for (int t = 0; t < 3; ++t) {
        int rid = 3 * w + t;
        int R   = rid * 16;
        const float* wsrc = nullptr; const float* bsrc = nullptr; int row0 = 0;
        if (rid < 8)        { wsrc = wv; bsrc = bv; row0 = R; }
        else if (rid == 8)  { wsrc = wq; bsrc = bq; row0 = 0; }
        else if (rid == 10) { wsrc = wk; bsrc = bk; row0 = 0; }
        live[t] = (wsrc != nullptr);
        #pragma unroll
        for (int r = 0; r < 4; ++r)
            biasv[t][r] = live[t] ? bsrc[row0 + quad * 4 + r] : 0.0f;
        if (live[t]) {
            #pragma unroll
            for (int ks = 0; ks < 4; ++ks) {
                const float* src = wsrc + (size_t)(row0 + nn) * NC + ks * 32 + quad * 8;
                f32x4 wa = *(const f32x4*)src;
                f32x4 wb = *(const f32x4*)(src + 4);
                s16x8 f;
                #pragma unroll
                for (int j = 0; j < 4; ++j) { f[j] = bf16s(wa[j]); f[j + 4] = bf16s(wb[j]); }
                af[t][ks] = f;
            }
        }
    }
    __syncthreads();

    f32x4 acc[3][2];
    #pragma unroll
    for (int t = 0; t < 3; ++t)
        #pragma unroll
        for (int nt = 0; nt < 2; ++nt)
            acc[t][nt] = biasv[t];

    #pragma unroll
    for (int nt = 0; nt < 2; ++nt) {
        s16x8 bf[4];
        #pragma unroll
        for (int ks = 0; ks < 4; ++ks)
            bf[ks] = *(const s16x8*)&xsT[(nt * 16 + nn) * 136 + ks * 32 + quad * 8];
        #pragma unroll
        for (int t = 0; t < 3; ++t)
            if (live[t])
                #pragma unroll
                for (int ks = 0; ks < 4; ++ks)
                    acc[t][nt] = __builtin_amdgcn_mfma_f32_16x16x32_bf16(af[t][ks], bf[ks], acc[t][nt], 0, 0, 0);
    }

    #pragma unroll
    for (int t = 0; t < 3; ++t) {
        if (!live[t]) continue;
        int R = (3 * w + t) * 16;
        #pragma unroll
        for (int nt = 0; nt < 2; ++nt) {
            int n = n0 + nt * 16 + nn;
            #pragma unroll
            for (int r = 0; r < 4; ++r) {
                short v = bf16s(acc[t][nt][r]);
                int row = R + quad * 4 + r;      // quad-uniform
                if (row < 128)
                    vt[((size_t)(b * NC + row)) * NNPOS + n] = v;
                else if (row < 144)
                    qb[((size_t)(b * NNPOS) + n) * 16 + (row - 128)] = v;
                else
                    kb[((size_t)(b * NNPOS) + n) * 16 + (row - 160)] = v;
            }
        }
    }
}

// ------------------------------------------------------------------
// Kernel 2: flash attention, S^T formulation, mfma 32x32x16.
// BARRIER-FREE main loop: V B-frags come straight from global (L1/L2
// resident: 1 MB per batch, 16 KB per chunk) into registers; no LDS.
// Each wave owns 64 queries (2 x 32-q tiles) so every V frag feeds two
// MFMAs. Block = 4 waves = 256 q. Split-K x8 -> grid 512 (2 blocks/CU,
// 8 waves/CU, no __syncthreads anywhere).
//  - scores: S^T = K.Q^T (A=K rows=keys, B=Q rows=queries, K-dim=16=CQ)
//  - 32x32 C/D: col=lane&31 (=q), row=(reg&3)+8*(reg>>2)+4*(lane>>5)
//  - P -> PV A-frag via bf16 pack + half-lane swap (shfl_xor 32)
// ------------------------------------------------------------------
__global__ __launch_bounds__(256, 2) void attn_kernel(
    const short* __restrict__ qb, const short* __restrict__ kb,
    const short* __restrict__ vt,
    unsigned short* __restrict__ Ow, float* __restrict__ lw)
{
    const int qblk = blockIdx.x;   // 0..15
    const int s    = blockIdx.y;   // 0..KSP-1
    const int b    = blockIdx.z;
    const int tid  = threadIdx.x;
    const int w = tid >> 6, lane = tid & 63, h = lane >> 5, c31 = lane & 31;

    const int q0 = qblk * QBLK + w * 64;

    // Q B-frags for the wave's two 32-q tiles (held all kernel)
    s16x8 bq0 = *(const s16x8*)(qb + ((size_t)(b * NNPOS) + q0      + c31) * 16 + h * 8);
    s16x8 bq1 = *(const s16x8*)(qb + ((size_t)(b * NNPOS) + q0 + 32 + c31) * 16 + h * 8);

    f32x16 acc[2][4];
    #pragma unroll
    for (int qt = 0; qt < 2; ++qt)
        #pragma unroll
        for (int ct = 0; ct < 4; ++ct)
            #pragma unroll
            for (int r = 0; r < 16; ++r) acc[qt][ct][r] = 0.0f;
    float lp[2] = {0.f, 0.f};

    const int mbase = s * (NNPOS / KSP);
    const short* vbase = vt + (size_t)(b * NC) * NNPOS;

    for (int it = 0; it < (NNPOS / KSP) / 64; ++it) {
        const int m0 = mbase + it * 64;

        // K A-frags (coalesced: 64 lanes cover 1KB contiguous)
        s16x8 ak0 = *(const s16x8*)(kb + ((size_t)(b * NNPOS) + m0      + c31) * 16 + h * 8);
        s16x8 ak1 = *(const s16x8*)(kb + ((size_t)(b * NNPOS) + m0 + 32 + c31) * 16 + h * 8);

        // V B-frags, first half (kp=0,1): issue early, consumed after exp
        s16x8 vb0[4][2];
        #pragma unroll
        for (int ct = 0; ct < 4; ++ct)
            #pragma unroll
            for (int k2 = 0; k2 < 2; ++k2)
                vb0[ct][k2] = *(const s16x8*)(vbase +
                    (size_t)(ct * 32 + c31) * NNPOS + m0 + k2 * 16 + h * 8);

        // scores + exp + pack + half-lane swap -> PV A-frags
        s16x8 pa[2][4];
        #pragma unroll
        for (int qt = 0; qt < 2; ++qt) {
            s16x8 bqt = qt ? bq1 : bq0;
            f32x16 z;
            #pragma unroll
            for (int r = 0; r < 16; ++r) z[r] = 0.0f;
            f32x16 s0 = __builtin_amdgcn_mfma_f32_32x32x16_bf16(ak0, bqt, z, 0, 0, 0);
            f32x16 s1 = __builtin_amdgcn_mfma_f32_32x32x16_bf16(ak1, bqt, z, 0, 0, 0);
            int d[16];
            #pragma unroll
            for (int i = 0; i < 8; ++i) {
                float p0 = __expf(fminf(s0[2 * i], 80.f));
                float p1 = __expf(fminf(s0[2 * i + 1], 80.f));
                lp[qt] += p0 + p1;
                d[i] = packbf2(p0, p1);
            }
            #pragma unroll
            for (int i = 0; i < 8; ++i) {
                float p0 = __expf(fminf(s1[2 * i], 80.f));
                float p1 = __expf(fminf(s1[2 * i + 1], 80.f));
                lp[qt] += p0 + p1;
                d[8 + i] = packbf2(p0, p1);
            }
            int xw[16];
            #pragma unroll
            for (int i = 0; i < 16; ++i) xw[i] = __shfl_xor(d[i], 32, 64);
            #pragma unroll
            for (int kp = 0; kp < 4; ++kp) {
                int e = kp * 4;
                union { int i[4]; s16x8 v; } u;
                u.i[0] = h ? xw[e + 2] : d[e];
                u.i[1] = h ? xw[e + 3] : d[e + 1];
                u.i[2] = h ? d[e + 2]  : xw[e];
                u.i[3] = h ? d[e + 3]  : xw[e + 1];
                pa[qt][kp] = u.v;
            }
        }

        // PV first half (keys 0..31 of chunk)
        #pragma unroll
        for (int ct = 0; ct < 4; ++ct)
            #pragma unroll
            for (int k2 = 0; k2 < 2; ++k2)
                #pragma unroll
                for (int qt = 0; qt < 2; ++qt)
                    acc[qt][ct] = __builtin_amdgcn_mfma_f32_32x32x16_bf16(
                        pa[qt][k2], vb0[ct][k2], acc[qt][ct], 0, 0, 0);

        // V B-frags, second half (kp=2,3), then PV
        s16x8 vb1[4][2];
        #pragma unroll
        for (int ct = 0; ct < 4; ++ct)
            #pragma unroll
            for (int k2 = 0; k2 < 2; ++k2)
                vb1[ct][k2] = *(const s16x8*)(vbase +
                    (size_t)(ct * 32 + c31) * NNPOS + m0 + (2 + k2) * 16 + h * 8);
        #pragma unroll
        for (int ct = 0; ct < 4; ++ct)
            #pragma unroll
            for (int k2 = 0; k2 < 2; ++k2)
                #pragma unroll
                for (int qt = 0; qt < 2; ++qt)
                    acc[qt][ct] = __builtin_amdgcn_mfma_f32_32x32x16_bf16(
                        pa[qt][2 + k2], vb1[ct][k2], acc[qt][ct], 0, 0, 0);
    }

    // l: both half-lanes hold partial for q = qt*32 + c31
    #pragma unroll
    for (int qt = 0; qt < 2; ++qt) {
        lp[qt] += __shfl_xor(lp[qt], 32, 64);
        if (lane < 32)
            lw[((size_t)(b * KSP + s)) * NNPOS + q0 + qt * 32 + c31] = lp[qt];
    }

    // O partial: [b][s][n][c] bf16
    #pragma unroll
    for (int qt = 0; qt < 2; ++qt)
        #pragma unroll
        for (int ct = 0; ct < 4; ++ct)
            #pragma unroll
            for (int r = 0; r < 16; ++r) {
                int q = q0 + qt * 32 + (r & 3) + 8 * (r >> 2) + 4 * h;
                Ow[(((size_t)(b * KSP + s)) * NNPOS + q) * NC + ct * 32 + c31] =
                    (unsigned short)bf16s(acc[qt][ct][r]);
            }
}

// ------------------------------------------------------------------
// Kernel 3: combine split-K partials + epilogue.
// out[b][c][n] = gamma * (sum_s O[b][s][n][c]) / (sum_s l[b][s][n]) + x
// ------------------------------------------------------------------
__global__ __launch_bounds__(256) void combine_kernel(
    const unsigned short* __restrict__ Ow, const float* __restrict__ lw,
    const float* __restrict__ x, const float* __restrict__ gamma,
    float* __restrict__ out)
{
    const int n0  = blockIdx.x * 64;
    const int b   = blockIdx.y;
    const int tid = threadIdx.x;

    __shared__ float ot[128 * 65 + 64];
    float* lsum = ot + 128 * 65;

    if (tid < 64) {
        float sl = 0.f;
        #pragma unroll
        for (int sI = 0; sI < KSP; ++sI)
            sl += lw[((size_t)(b * KSP + sI)) * NNPOS + n0 + tid];
        lsum[tid] = sl;
    }
    __syncthreads();

    #pragma unroll
    for (int p = 0; p < 16; ++p) {
        int e = tid + p * 256;          // over 64n x 64 c-pairs
        int cp = e & 63, n = e >> 6;
        float a0 = 0.f, a1 = 0.f;
        #pragma unroll
        for (int sI = 0; sI < KSP; ++sI) {
            const unsigned short* src = Ow +
                (((size_t)(b * KSP + sI)) * NNPOS + n0 + n) * NC + cp * 2;
            ushort2 u = *(const ushort2*)src;
            a0 += bf2f(u.x);
            a1 += bf2f(u.y);
        }
        float inv = 1.0f / lsum[n];
        ot[(cp * 2) * 65 + n]     = a0 * inv;
        ot[(cp * 2 + 1) * 65 + n] = a1 * inv;
    }
    __syncthreads();

    const float g = gamma[0];
    #pragma unroll
    for (int p = 0; p < 32; ++p) {
        int e = tid + p * 256;          // over 128c x 64n
        int n = e & 63, c = e >> 6;
        size_t a = ((size_t)(b * NC + c)) * NNPOS + n0 + n;
        out[a] = g * ot[c * 65 + n] + x[a];
    }
}

// ------------------------------------------------------------------
extern "C" void kernel_launch(void* const* d_in, const int* in_sizes, int n_in,
                              void* d_out, int out_size, void* d_ws, size_t ws_size,
                              hipStream_t stream) {
    const float* x     = (const float*)d_in[0];
    const float* wq    = (const float*)d_in[1];
    const float* bq    = (const float*)d_in[2];
    const float* wk    = (const float*)d_in[3];
    const float* bk    = (const float*)d_in[4];
    const float* wv    = (const float*)d_in[5];
    const float* bv    = (const float*)d_in[6];
    const float* gamma = (const float*)d_in[7];
    float* out = (float*)d_out;

    // ws: qb 512KB | kb 512KB | vt 4MB | Ow 32MB | lw 512KB  (~37.5MB)
    short* qb = (short*)d_ws;
    short* kb = qb + (size_t)NB * NNPOS * 16;
    short* vt = kb + (size_t)NB * NNPOS * 16;
    unsigned short* Ow = (unsigned short*)(vt + (size_t)NB * NC * NNPOS);
    float* lw = (float*)(Ow + (size_t)NB * KSP * NNPOS * NC);

    qkv_kernel<<<dim3(128, NB), 256, 0, stream>>>(x, wq, bq, wk, bk, wv, bv, qb, kb, vt);
    attn_kernel<<<dim3(NNPOS / QBLK, KSP, NB), 256, 0, stream>>>(qb, kb, vt, Ow, lw);
    combine_kernel<<<dim3(NNPOS / 64, NB), 256, 0, stream>>>(Ow, lw, x, gamma, out);
}

// Round 6
// 127.050 us; speedup vs baseline: 1.0527x; 1.0527x over previous
//
#include <hip/hip_runtime.h>
#include <hip/hip_bf16.h>

typedef float f32x4  __attribute__((ext_vector_type(4)));
typedef float f32x16 __attribute__((ext_vector_type(16)));
typedef short s16x8  __attribute__((ext_vector_type(8)));

#define NB 4
#define NC 128
#define NNPOS 4096
#define KSP 8          // block-level key split (also the XCD partition key)
#define LOG2E 1.44269504088896f

__device__ __forceinline__ short bf16s(float x) {
    __hip_bfloat16 h = __float2bfloat16(x);
    return *reinterpret_cast<short*>(&h);
}
__device__ __forceinline__ int packbf2(float lo, float hi) {
    __hip_bfloat162 t = __float22bfloat162_rn(float2{lo, hi});
    return *reinterpret_cast<int*>(&t);
}
__device__ __forceinline__ float bf2f(unsigned short u) {
    unsigned int v = ((unsigned int)u) << 16;
    return *reinterpret_cast<float*>(&v);
}
// base-2 exp: native v_exp_f32 (q was pre-scaled by log2e)
__device__ __forceinline__ float exp2fast(float x) {
    return __builtin_amdgcn_exp2f(x);
}

// ------------------------------------------------------------------
// Kernel 1: QKV projection via bf16 MFMA 16x16x32.
// qb/kb: [b][n][16] bf16 (q pre-scaled by log2e so attn uses exp2).
// vt: B-frag tile order [b][key/16][c/32][c%32][key%16] so attn's PV
//     B-frag loads are 64 lanes x 16B = 2KB contiguous (coalesced).
// ------------------------------------------------------------------
__global__ __launch_bounds__(256) void qkv_kernel(
    const float* __restrict__ x,
    const float* __restrict__ wq, const float* __restrict__ bq,
    const float* __restrict__ wk, const float* __restrict__ bk,
    const float* __restrict__ wv, const float* __restrict__ bv,
    short* __restrict__ qb, short* __restrict__ kb, short* __restrict__ vt)
{
    const int n0  = blockIdx.x * 32;
    const int b   = blockIdx.y;
    const int tid = threadIdx.x;
    const int w = tid >> 6, lane = tid & 63, quad = lane >> 4, nn = lane & 15;

    __shared__ __align__(16) short xsT[32 * 136];

    #pragma unroll
    for (int p = 0; p < 4; ++p) {
        int idx = tid + p * 256;
        int cc = idx >> 3, n4 = (idx & 7) * 4;
        f32x4 xv = *(const f32x4*)&x[((size_t)(b * NC + cc)) * NNPOS + n0 + n4];
        #pragma unroll
        for (int j = 0; j < 4; ++j)
            xsT[(n4 + j) * 136 + cc] = bf16s(xv[j]);
    }

    s16x8 af[3][4];
    bool  live[3];
    f32x4 biasv[3];
    #pragma unroll
    for (int t = 0; t < 3; ++t) {
        int rid = 3 * w + t;
        int R   = rid * 16;
        const float* wsrc = nullptr; const float* bsrc = nullptr; int row0 = 0;
        float scale = 1.0f;
        if (rid < 8)        { wsrc = wv; bsrc = bv; row0 = R; }
        else if (rid == 8)  { wsrc = wq; bsrc = bq; row0 = 0; scale = LOG2E; }
        else if (rid == 10) { wsrc = wk; bsrc = bk; row0 = 0; }
        live[t] = (wsrc != nullptr);
        #pragma unroll
        for (int r = 0; r < 4; ++r)
            biasv[t][r] = live[t] ? scale * bsrc[row0 + quad * 4 + r] : 0.0f;
        if (live[t]) {
            #pragma unroll
            for (int ks = 0; ks < 4; ++ks) {
                const float* src = wsrc + (size_t)(row0 + nn) * NC + ks * 32 + quad * 8;
                f32x4 wa = *(const f32x4*)src;
                f32x4 wb = *(const f32x4*)(src + 4);
                s16x8 f;
                #pragma unroll
                for (int j = 0; j < 4; ++j) {
                    f[j]     = bf16s(scale * wa[j]);
                    f[j + 4] = bf16s(scale * wb[j]);
                }
                af[t][ks] = f;
            }
        }
    }
    __syncthreads();

    f32x4 acc[3][2];
    #pragma unroll
    for (int t = 0; t < 3; ++t)
        #pragma unroll
        for (int nt = 0; nt < 2; ++nt)
            acc[t][nt] = biasv[t];

    #pragma unroll
    for (int nt = 0; nt < 2; ++nt) {
        s16x8 bf[4];
        #pragma unroll
        for (int ks = 0; ks < 4; ++ks)
            bf[ks] = *(const s16x8*)&xsT[(nt * 16 + nn) * 136 + ks * 32 + quad * 8];
        #pragma unroll
        for (int t = 0; t < 3; ++t)
            if (live[t])
                #pragma unroll
                for (int ks = 0; ks < 4; ++ks)
                    acc[t][nt] = __builtin_amdgcn_mfma_f32_16x16x32_bf16(af[t][ks], bf[ks], acc[t][nt], 0, 0, 0);
    }

    #pragma unroll
    for (int t = 0; t < 3; ++t) {
        if (!live[t]) continue;
        int R = (3 * w + t) * 16;
        #pragma unroll
        for (int nt = 0; nt < 2; ++nt) {
            int n = n0 + nt * 16 + nn;
            int kg = (n0 + nt * 16) >> 4;      // uniform per (nt)
            #pragma unroll
            for (int r = 0; r < 4; ++r) {
                short v = bf16s(acc[t][nt][r]);
                int row = R + quad * 4 + r;      // quad-uniform branch
                if (row < 128) {
                    // swizzled tile store: [b][kg][ct][c31][kk]
                    int ct = row >> 5, c31r = row & 31;
                    vt[((((size_t)b * 256 + kg) * 4 + ct) * 32 + c31r) * 16 + nn] = v;
                } else if (row < 144)
                    qb[((size_t)(b * NNPOS) + n) * 16 + (row - 128)] = v;
                else
                    kb[((size_t)(b * NNPOS) + n) * 16 + (row - 160)] = v;
            }
        }
    }
}

// ------------------------------------------------------------------
// Kernel 2: flash attention, S^T formulation, mfma 32x32x16.
// Barrier-free, LDS-free. Each wave owns 32 queries; block = 4 q-tiles
// sharing the same key-split (L1 reuse of V chunks). blockIdx.x = split
// so XCD (~ id%8) sees only one split: per-XCD V+K working set ~640KB.
// All V frag loads are 2KB-contiguous (vt is pre-swizzled).
//  - scores: S^T = K.Q^T (A=K rows=keys, B=Q rows=queries, K-dim=16=CQ)
//  - 32x32 C/D: col=lane&31 (=q), row=(reg&3)+8*(reg>>2)+4*(lane>>5)
//  - P -> PV A-frag via bf16 pack + half-lane swap (shfl_xor 32)
//  - q pre-scaled by log2e -> native v_exp_f32 (base 2) for softmax
// ------------------------------------------------------------------
__global__ __launch_bounds__(256, 2) void attn_kernel(
    const short* __restrict__ qb, const short* __restrict__ kb,
    const short* __restrict__ vt,
    unsigned short* __restrict__ Ow, float* __restrict__ lw)
{
    const int s   = blockIdx.x;    // key split 0..7  (XCD partition)
    const int b   = blockIdx.z;
    const int tid = threadIdx.x;
    const int w = tid >> 6, lane = tid & 63, h = lane >> 5, c31 = lane & 31;

    const int qt = blockIdx.y * 4 + w;    // q-tile 0..127
    const int q0 = qt * 32;

    // Q B-frag (held all kernel)
    s16x8 bq = *(const s16x8*)(qb + ((size_t)(b * NNPOS) + q0 + c31) * 16 + h * 8);

    f32x16 acc[4];
    #pragma unroll
    for (int ct = 0; ct < 4; ++ct)
        #pragma unroll
        for (int r = 0; r < 16; ++r) acc[ct][r] = 0.0f;
    float lp = 0.0f;

    const short* kbp = kb + (size_t)(b * NNPOS) * 16;
    const short* vbp = vt + (size_t)b * (256 * 4 * 512);
    const int mbase = s * (NNPOS / KSP);
    const int kgbase = mbase >> 4;

    #pragma unroll 2
    for (int it = 0; it < (NNPOS / KSP) / 64; ++it) {
        const int m0 = mbase + it * 64;
        const int kg0 = kgbase + it * 4;

        // K A-frags first (score MFMA waits only on these)
        s16x8 ak0 = *(const s16x8*)(kbp + (size_t)(m0      + c31) * 16 + h * 8);
        s16x8 ak1 = *(const s16x8*)(kbp + (size_t)(m0 + 32 + c31) * 16 + h * 8);

        // all 16 V B-frags: each 2KB contiguous per wave
        s16x8 vb[4][4];   // [kp][ct]
        #pragma unroll
        for (int kp = 0; kp < 4; ++kp)
            #pragma unroll
            for (int ct = 0; ct < 4; ++ct)
                vb[kp][ct] = *(const s16x8*)(vbp +
                    (((size_t)(kg0 + kp) * 4 + ct) << 9) + (c31 << 4) + (h << 3));

        // scores (exp2 domain), pack, half-lane swap -> PV A-frags
        f32x16 z;
        #pragma unroll
        for (int r = 0; r < 16; ++r) z[r] = 0.0f;
        f32x16 s0 = __builtin_amdgcn_mfma_f32_32x32x16_bf16(ak0, bq, z, 0, 0, 0);
        f32x16 s1 = __builtin_amdgcn_mfma_f32_32x32x16_bf16(ak1, bq, z, 0, 0, 0);

        int d[16];
        #pragma unroll
        for (int i = 0; i < 8; ++i) {
            float p0 = exp2fast(fminf(s0[2 * i], 126.f));
            float p1 = exp2fast(fminf(s0[2 * i + 1], 126.f));
            lp += p0 + p1;
            d[i] = packbf2(p0, p1);
        }
        #pragma unroll
        for (int i = 0; i < 8; ++i) {
            float p0 = exp2fast(fminf(s1[2 * i], 126.f));
            float p1 = exp2fast(fminf(s1[2 * i + 1], 126.f));
            lp += p0 + p1;
            d[8 + i] = packbf2(p0, p1);
        }
        int xw[16];
        #pragma unroll
        for (int i = 0; i < 16; ++i) xw[i] = __shfl_xor(d[i], 32, 64);

        s16x8 pa[4];
        #pragma unroll
        for (int kp = 0; kp < 4; ++kp) {
            int e = kp * 4;
            union { int i[4]; s16x8 v; } u;
            u.i[0] = h ? xw[e + 2] : d[e];
            u.i[1] = h ? xw[e + 3] : d[e + 1];
            u.i[2] = h ? d[e + 2]  : xw[e];
            u.i[3] = h ? d[e + 3]  : xw[e + 1];
            pa[kp] = u.v;
        }

        // PV: D[q][c] += P.V^T
        #pragma unroll
        for (int kp = 0; kp < 4; ++kp)
            #pragma unroll
            for (int ct = 0; ct < 4; ++ct)
                acc[ct] = __builtin_amdgcn_mfma_f32_32x32x16_bf16(
                    pa[kp], vb[kp][ct], acc[ct], 0, 0, 0);
    }

    // l: both half-lanes hold the partial for q = q0 + c31
    lp += __shfl_xor(lp, 32, 64);
    if (lane < 32)
        lw[((size_t)(b * KSP + s)) * NNPOS + q0 + c31] = lp;

    // O partial: [b][s][n][c] bf16
    #pragma unroll
    for (int ct = 0; ct < 4; ++ct)
        #pragma unroll
        for (int r = 0; r < 16; ++r) {
            int q = q0 + (r & 3) + 8 * (r >> 2) + 4 * h;
            Ow[(((size_t)(b * KSP + s)) * NNPOS + q) * NC + ct * 32 + c31] =
                (unsigned short)bf16s(acc[ct][r]);
        }
}

// ------------------------------------------------------------------
// Kernel 3: combine split-K partials + epilogue.
// out[b][c][n] = gamma * (sum_s O[b][s][n][c]) / (sum_s l[b][s][n]) + x
// ------------------------------------------------------------------
__global__ __launch_bounds__(256) void combine_kernel(
    const unsigned short* __restrict__ Ow, const float* __restrict__ lw,
    const float* __restrict__ x, const float* __restrict__ gamma,
    float* __restrict__ out)
{
    const int n0  = blockIdx.x * 64;
    const int b   = blockIdx.y;
    const int tid = threadIdx.x;

    __shared__ float ot[128 * 65 + 64];
    float* lsum = ot + 128 * 65;

    if (tid < 64) {
        float sl = 0.f;
        #pragma unroll
        for (int sI = 0; sI < KSP; ++sI)
            sl += lw[((size_t)(b * KSP + sI)) * NNPOS + n0 + tid];
        lsum[tid] = sl;
    }
    __syncthreads();

    #pragma unroll
    for (int p = 0; p < 16; ++p) {
        int e = tid + p * 256;          // over 64n x 64 c-pairs
        int cp = e & 63, n = e >> 6;
        float a0 = 0.f, a1 = 0.f;
        #pragma unroll
        for (int sI = 0; sI < KSP; ++sI) {
            const unsigned short* src = Ow +
                (((size_t)(b * KSP + sI)) * NNPOS + n0 + n) * NC + cp * 2;
            ushort2 u = *(const ushort2*)src;
            a0 += bf2f(u.x);
            a1 += bf2f(u.y);
        }
        float inv = 1.0f / lsum[n];
        ot[(cp * 2) * 65 + n]     = a0 * inv;
        ot[(cp * 2 + 1) * 65 + n] = a1 * inv;
    }
    __syncthreads();

    const float g = gamma[0];
    #pragma unroll
    for (int p = 0; p < 32; ++p) {
        int e = tid + p * 256;          // over 128c x 64n
        int n = e & 63, c = e >> 6;
        size_t a = ((size_t)(b * NC + c)) * NNPOS + n0 + n;
        out[a] = g * ot[c * 65 + n] + x[a];
    }
}

// ------------------------------------------------------------------
extern "C" void kernel_launch(void* const* d_in, const int* in_sizes, int n_in,
                              void* d_out, int out_size, void* d_ws, size_t ws_size,
                              hipStream_t stream) {
    const float* x     = (const float*)d_in[0];
    const float* wq    = (const float*)d_in[1];
    const float* bq    = (const float*)d_in[2];
    const float* wk    = (const float*)d_in[3];
    const float* bk    = (const float*)d_in[4];
    const float* wv    = (const float*)d_in[5];
    const float* bv    = (const float*)d_in[6];
    const float* gamma = (const float*)d_in[7];
    float* out = (float*)d_out;

    // ws: qb 512KB | kb 512KB | vt 4MB | Ow 32MB | lw 512KB
    short* qb = (short*)d_ws;
    short* kb = qb + (size_t)NB * NNPOS * 16;
    short* vt = kb + (size_t)NB * NNPOS * 16;
    unsigned short* Ow = (unsigned short*)(vt + (size_t)NB * NC * NNPOS);
    float* lw = (float*)(Ow + (size_t)NB * KSP * NNPOS * NC);

    qkv_kernel<<<dim3(128, NB), 256, 0, stream>>>(x, wq, bq, wk, bk, wv, bv, qb, kb, vt);
    attn_kernel<<<dim3(KSP, 32, NB), 256, 0, stream>>>(qb, kb, vt, Ow, lw);
    combine_kernel<<<dim3(NNPOS / 64, NB), 256, 0, stream>>>(Ow, lw, x, gamma, out);
}